// Round 9
// baseline (289.459 us; speedup 1.0000x reference)
//
#include <hip/hip_runtime.h>

#define N_NODES 100000
#define N_EVENTS 100000
#define D 128
#define KTOT 640
#define NP 512
#define BM 64

// ---- workspace layout (bytes) ----
#define OFF_AGGR 0                                 // bf16 [N][384] = 76,800,000
#define OFF_CNT  76800000
#define OFF_LAST (OFF_CNT  + N_NODES * 4)
#define OFF_OFFS (OFF_LAST + N_NODES * 4)
#define OFF_CUR  (OFF_OFFS + N_NODES * 4)
#define OFF_CSR  (OFF_CUR  + N_NODES * 4)          // int4 * 2E = 3,200,000
#define OFF_BP   (OFF_CSR  + 2 * N_EVENTS * 16)    // bf16 512*640 = 655,360
#define OFF_PART (OFF_BP   + NP * KTOT * 2)        // 98 ints

#define SCAN_BLOCKS 98   // ceil(100000 / 1024)

typedef __attribute__((ext_vector_type(8))) short bf16x8;
typedef __attribute__((ext_vector_type(4))) float f32x4;

__device__ __forceinline__ short f2bf(float x) {
    unsigned u = __float_as_uint(x);
    u = (u + 0x7FFFu + ((u >> 16) & 1u)) >> 16;
    return (short)u;
}

__device__ __forceinline__ bf16x8 cvt8(const float4& x0, const float4& x1) {
    bf16x8 h;
    h[0] = f2bf(x0.x); h[1] = f2bf(x0.y); h[2] = f2bf(x0.z); h[3] = f2bf(x0.w);
    h[4] = f2bf(x1.x); h[5] = f2bf(x1.y); h[6] = f2bf(x1.z); h[7] = f2bf(x1.w);
    return h;
}

#define MFMA(a, b, c) __builtin_amdgcn_mfma_f32_16x16x32_bf16(a, b, c, 0, 0, 0)

// ---- kernel 1: zero counters, build packed weight matrix Bp[512][640] bf16 ----
// Bp rows (n): 0-127 -> r (wih | whh), 128-255 -> z, 256-383 -> xn (k<512),
// 384-511 -> hn (k>=512 only)
__global__ __launch_bounds__(256) void k_init(unsigned* __restrict__ cnt,
                                              int* __restrict__ lastmax,
                                              const float* __restrict__ wih,
                                              const float* __restrict__ whh,
                                              short* __restrict__ bp) {
    int i = blockIdx.x * blockDim.x + threadIdx.x;
    int stride = gridDim.x * blockDim.x;
    for (int j = i; j < N_NODES; j += stride) { cnt[j] = 0u; lastmax[j] = 0; }
    for (int j = i; j < NP * KTOT; j += stride) {
        int n = j / KTOT, k = j - n * KTOT;
        float v = 0.f;
        if (n < 384) {
            if (k < 512) v = wih[n * 512 + k];
            else if (n < 256) v = whh[n * 128 + (k - 512)];
        } else if (k >= 512) {
            v = whh[(n - 128) * 128 + (k - 512)];
        }
        bp[j] = f2bf(v);
    }
}

// ---- kernel 2a: per-node degree count + last_update max ----
__global__ __launch_bounds__(256) void k_count(const int* __restrict__ src,
                                               const int* __restrict__ dst,
                                               const int* __restrict__ t,
                                               unsigned* __restrict__ cnt,
                                               int* __restrict__ lastmax) {
    int e = blockIdx.x * blockDim.x + threadIdx.x;
    if (e < N_EVENTS) {
        int s = src[e], d = dst[e], te = t[e];
        atomicAdd(&cnt[s], 1u);
        atomicAdd(&cnt[d], 1u);
        atomicMax(&lastmax[s], te);
        atomicMax(&lastmax[d], te);
    }
}

// ---- kernel 2b-1: per-block partial sums (1024 nodes/block) ----
__global__ __launch_bounds__(256) void k_scanA(const unsigned* __restrict__ cnt,
                                               int* __restrict__ partial) {
    const int b = blockIdx.x, tid = threadIdx.x;
    const int base = b * 1024 + tid * 4;
    int s = 0;
    if (base + 3 < N_NODES) {
        int4 c = *(const int4*)((const int*)cnt + base);
        s = c.x + c.y + c.z + c.w;
    } else {
        for (int k = 0; k < 4; ++k)
            if (base + k < N_NODES) s += (int)cnt[base + k];
    }
#pragma unroll
    for (int off = 32; off; off >>= 1) s += __shfl_down(s, off, 64);
    __shared__ int ws[4];
    if ((tid & 63) == 0) ws[tid >> 6] = s;
    __syncthreads();
    if (tid == 0) partial[b] = ws[0] + ws[1] + ws[2] + ws[3];
}

// ---- kernel 2b-2: exclusive scan of the 98 partials (tiny) ----
__global__ __launch_bounds__(128) void k_scanB(int* __restrict__ partial) {
    __shared__ int p[128];
    const int tid = threadIdx.x;
    p[tid] = (tid < SCAN_BLOCKS) ? partial[tid] : 0;
    __syncthreads();
    if (tid == 0) {
        int run = 0;
        for (int i = 0; i < SCAN_BLOCKS; ++i) { int v = p[i]; p[i] = run; run += v; }
    }
    __syncthreads();
    if (tid < SCAN_BLOCKS) partial[tid] = p[tid];
}

// ---- kernel 2b-3: block-local scan + offset -> offs, cursor; also emits
//      last_update output ----
__global__ __launch_bounds__(256) void k_scanC(const unsigned* __restrict__ cnt,
                                               const int* __restrict__ partial,
                                               int* __restrict__ offs,
                                               int* __restrict__ cursor,
                                               const int* __restrict__ lastmax,
                                               float* __restrict__ outLast) {
    __shared__ int sums[256];
    const int b = blockIdx.x, tid = threadIdx.x;
    const int base = b * 1024 + tid * 4;
    int c0 = 0, c1 = 0, c2 = 0, c3 = 0;
    if (base + 3 < N_NODES) {
        int4 c = *(const int4*)((const int*)cnt + base);
        c0 = c.x; c1 = c.y; c2 = c.z; c3 = c.w;
    } else {
        if (base     < N_NODES) c0 = (int)cnt[base];
        if (base + 1 < N_NODES) c1 = (int)cnt[base + 1];
        if (base + 2 < N_NODES) c2 = (int)cnt[base + 2];
        if (base + 3 < N_NODES) c3 = (int)cnt[base + 3];
    }
    sums[tid] = c0 + c1 + c2 + c3;
    __syncthreads();
    for (int off = 1; off < 256; off <<= 1) {
        int v = (tid >= off) ? sums[tid - off] : 0;
        __syncthreads();
        sums[tid] += v;
        __syncthreads();
    }
    int run = partial[b] + (tid > 0 ? sums[tid - 1] : 0);
    const int o0 = run, o1 = o0 + c0, o2 = o1 + c1, o3 = o2 + c2;
    if (base + 3 < N_NODES) {
        *(int4*)(offs + base)   = make_int4(o0, o1, o2, o3);
        *(int4*)(cursor + base) = make_int4(o0, o1, o2, o3);
        int4 lm = *(const int4*)(lastmax + base);
        float4 lo = make_float4((float)lm.x, (float)lm.y, (float)lm.z, (float)lm.w);
        *(float4*)(outLast + base) = lo;
    } else {
        if (base     < N_NODES) { offs[base]     = o0; cursor[base]     = o0; outLast[base]     = (float)lastmax[base]; }
        if (base + 1 < N_NODES) { offs[base + 1] = o1; cursor[base + 1] = o1; outLast[base + 1] = (float)lastmax[base + 1]; }
        if (base + 2 < N_NODES) { offs[base + 2] = o2; cursor[base + 2] = o2; outLast[base + 2] = (float)lastmax[base + 2]; }
        if (base + 3 < N_NODES) { offs[base + 3] = o3; cursor[base + 3] = o3; outLast[base + 3] = (float)lastmax[base + 3]; }
    }
}

// ---- kernel 2c: fill CSR records {other, t, e} ----
__global__ __launch_bounds__(256) void k_fill(const int* __restrict__ src,
                                              const int* __restrict__ dst,
                                              const int* __restrict__ t,
                                              int* __restrict__ cursor,
                                              int4* __restrict__ csr) {
    int e = blockIdx.x * blockDim.x + threadIdx.x;
    if (e < N_EVENTS) {
        int s = src[e], d = dst[e], te = t[e];
        int ps = atomicAdd(&cursor[s], 1);
        csr[ps] = make_int4(d, te, e, 0);
        int pd = atomicAdd(&cursor[d], 1);
        csr[pd] = make_int4(s, te, e, 0);
    }
}

// ---- kernel 3: gather-aggregate per node, write aggr bf16 [N][384] pre-divided ----
__global__ __launch_bounds__(128) void k_aggr(const float* __restrict__ mem,
                                              const float* __restrict__ raw,
                                              const int* __restrict__ lu,
                                              const float* __restrict__ tw,
                                              const float* __restrict__ tb,
                                              const int* __restrict__ offs,
                                              const unsigned* __restrict__ cnt,
                                              const int4* __restrict__ csr,
                                              unsigned short* __restrict__ aggr) {
    const int node = blockIdx.x;
    const int i = threadIdx.x;
    const unsigned deg = cnt[node];
    float a0 = 0.f, a1 = 0.f, a2 = 0.f;
    if (deg) {
        const int start = offs[node];
        const int lun = lu[node];
        const float wi = tw[i], bi = tb[i];
        for (unsigned j = 0; j < deg; ++j) {
            int4 rec = csr[start + j];
            const int other = rec.x, te = rec.y, e = rec.z;
            a0 += mem[other * D + i];
            a1 += raw[e * D + i];
            // match numpy: separate mul + add rounding (NO fma) before cos
            const float tr = (float)(te - lun);
            a2 += cosf(__fadd_rn(__fmul_rn(tr, wi), bi));
        }
        const float inv = 1.f / (float)deg;
        a0 *= inv; a1 *= inv; a2 *= inv;
    }
    aggr[node * 384 + i]       = (unsigned short)f2bf(a0);
    aggr[node * 384 + 128 + i] = (unsigned short)f2bf(a1);
    aggr[node * 384 + 256 + i] = (unsigned short)f2bf(a2);
}

// ---- kernel 4: fused concat-GEMM + GRU, single-barrier, free-running ----
// LDS A'[64][512] bf16: virtual cols 0-127 = mem raw, 128-511 = aggr.
// Physical slot within row: phys16 = virt16 ^ (row & 7)  (16B granularity).
// Staging: wave w stages whole rows 8j+w; lane l writes PHYSICAL slot l
// (contiguous 1024B per row per wave -> zero bank conflicts), sourcing
// virtual column l ^ (row&7).
//   S 0-3:  A cols 0-127 (masked by cnt>0) x B k 0-127   (wih; r,z,xn)
//   S 4-15: A cols 128-511                 x B k 128-511 (wih; r,z,xn)
//   S16-19: A cols 0-127 (raw)             x B k 512-639 (whh; r,z,hn)

template<int S>
__device__ __forceinline__ void kstep(const short* __restrict__ sA,
                                      int lr, int lk, int swz,
                                      const short* __restrict__ bR,
                                      const short* __restrict__ bZ,
                                      const short* __restrict__ bN,
                                      const bool* mv,
                                      f32x4* accR, f32x4* accZ, f32x4* accN) {
    constexpr int c0   = (S < 4) ? S * 32 : (S < 16 ? 128 + (S - 4) * 32 : (S - 16) * 32);
    constexpr int kOff = (S < 16) ? S * 32 : 512 + (S - 16) * 32;
    bf16x8 fR = *(const bf16x8*)(bR + kOff);
    bf16x8 fZ = *(const bf16x8*)(bZ + kOff);
    bf16x8 fN = *(const bf16x8*)(bN + kOff);
    const int aoff = lr * 1024 + ((c0 * 2 + lk * 16) ^ swz);
#pragma unroll
    for (int mt = 0; mt < 4; ++mt) {
        bf16x8 a = *(const bf16x8*)((const char*)sA + mt * 16384 + aoff);
        if constexpr (S < 4) { const bf16x8 z = {}; a = mv[mt] ? a : z; }
        accR[mt] = MFMA(a, fR, accR[mt]);
        accZ[mt] = MFMA(a, fZ, accZ[mt]);
        accN[mt] = MFMA(a, fN, accN[mt]);
    }
}

__global__ __launch_bounds__(512) void k_gemm_gru(const float* __restrict__ mem,
                                                  const unsigned short* __restrict__ aggr,
                                                  const unsigned* __restrict__ cnt,
                                                  const short* __restrict__ bp,
                                                  const float* __restrict__ bih,
                                                  const float* __restrict__ bhh,
                                                  float* __restrict__ out) {
    __shared__ short sA[64 * 512];     // 64 KB
    const int tid = threadIdx.x;
    const int node0 = blockIdx.x * BM;

    const int l = tid & 63, w = tid >> 6;
    const int lr = l & 15, lk = l >> 4;
    const int swz = (lr & 7) << 4;

    // ---- conflict-free staging: wave w stages rows 8j + w ----
#pragma unroll
    for (int j = 0; j < 8; ++j) {
        const int row = 8 * j + w;
        const int node = node0 + row;
        const int nc = node < N_NODES ? node : N_NODES - 1;
        const int v = l ^ (row & 7);            // virtual 16B-slot index
        bf16x8 h;
        if (v < 16) {
            const float4* p = (const float4*)(mem + nc * D + v * 8);
            h = cvt8(p[0], p[1]);
        } else {
            h = *(const bf16x8*)(aggr + nc * 384 + (v - 16) * 8);
        }
        *(bf16x8*)((char*)sA + row * 1024 + l * 16) = h;  // physical slot l
    }

    // per-mt row validity mask (cnt>0) for the x-part
    bool mv[4];
#pragma unroll
    for (int mt = 0; mt < 4; ++mt) {
        const int node = node0 + mt * 16 + lr;
        mv[mt] = cnt[node < N_NODES ? node : N_NODES - 1] != 0u;
    }

    f32x4 accR[4], accZ[4], accNx[4], accNh[4];
#pragma unroll
    for (int mt = 0; mt < 4; ++mt) {
        accR[mt]  = (f32x4){0.f, 0.f, 0.f, 0.f};
        accZ[mt]  = (f32x4){0.f, 0.f, 0.f, 0.f};
        accNx[mt] = (f32x4){0.f, 0.f, 0.f, 0.f};
        accNh[mt] = (f32x4){0.f, 0.f, 0.f, 0.f};
    }

    const short* bR = bp + (w * 16 + lr) * KTOT + lk * 8;
    const short* bZ = bp + ((8 + w) * 16 + lr) * KTOT + lk * 8;
    const short* bX = bp + ((16 + w) * 16 + lr) * KTOT + lk * 8;
    const short* bH = bp + ((24 + w) * 16 + lr) * KTOT + lk * 8;

    __syncthreads();

    // ---- 20 unrolled K-steps, no barriers ----
    kstep< 0>(sA, lr, lk, swz, bR, bZ, bX, mv, accR, accZ, accNx);
    kstep< 1>(sA, lr, lk, swz, bR, bZ, bX, mv, accR, accZ, accNx);
    kstep< 2>(sA, lr, lk, swz, bR, bZ, bX, mv, accR, accZ, accNx);
    kstep< 3>(sA, lr, lk, swz, bR, bZ, bX, mv, accR, accZ, accNx);
    kstep< 4>(sA, lr, lk, swz, bR, bZ, bX, mv, accR, accZ, accNx);
    kstep< 5>(sA, lr, lk, swz, bR, bZ, bX, mv, accR, accZ, accNx);
    kstep< 6>(sA, lr, lk, swz, bR, bZ, bX, mv, accR, accZ, accNx);
    kstep< 7>(sA, lr, lk, swz, bR, bZ, bX, mv, accR, accZ, accNx);
    kstep< 8>(sA, lr, lk, swz, bR, bZ, bX, mv, accR, accZ, accNx);
    kstep< 9>(sA, lr, lk, swz, bR, bZ, bX, mv, accR, accZ, accNx);
    kstep<10>(sA, lr, lk, swz, bR, bZ, bX, mv, accR, accZ, accNx);
    kstep<11>(sA, lr, lk, swz, bR, bZ, bX, mv, accR, accZ, accNx);
    kstep<12>(sA, lr, lk, swz, bR, bZ, bX, mv, accR, accZ, accNx);
    kstep<13>(sA, lr, lk, swz, bR, bZ, bX, mv, accR, accZ, accNx);
    kstep<14>(sA, lr, lk, swz, bR, bZ, bX, mv, accR, accZ, accNx);
    kstep<15>(sA, lr, lk, swz, bR, bZ, bX, mv, accR, accZ, accNx);
    kstep<16>(sA, lr, lk, swz, bR, bZ, bH, mv, accR, accZ, accNh);
    kstep<17>(sA, lr, lk, swz, bR, bZ, bH, mv, accR, accZ, accNh);
    kstep<18>(sA, lr, lk, swz, bR, bZ, bH, mv, accR, accZ, accNh);
    kstep<19>(sA, lr, lk, swz, bR, bZ, bH, mv, accR, accZ, accNh);

    // epilogue: GRU gates. C layout: col = l&15 (-> jcol), row = (l>>4)*4 + i.
    const int jcol = w * 16 + lr;
    const float br  = bih[jcol]       + bhh[jcol];
    const float bz  = bih[128 + jcol] + bhh[128 + jcol];
    const float bxn = bih[256 + jcol];
    const float bhn = bhh[256 + jcol];
#pragma unroll
    for (int mt = 0; mt < 4; ++mt) {
#pragma unroll
        for (int i = 0; i < 4; ++i) {
            const int node = node0 + mt * 16 + lk * 4 + i;
            if (node < N_NODES) {
                const float rp = accR[mt][i] + br;
                const float zp = accZ[mt][i] + bz;
                const float xn = accNx[mt][i] + bxn;
                const float hn = accNh[mt][i] + bhn;
                const float rg = 1.f / (1.f + expf(-rp));
                const float zg = 1.f / (1.f + expf(-zp));
                const float ng = tanhf(xn + rg * hn);
                const float mo = mem[node * D + jcol];
                out[node * D + jcol] = (1.f - zg) * ng + zg * mo;
            }
        }
    }
}

extern "C" void kernel_launch(void* const* d_in, const int* in_sizes, int n_in,
                              void* d_out, int out_size, void* d_ws, size_t ws_size,
                              hipStream_t stream) {
    const float* memory      = (const float*)d_in[0];
    const int*   last_update = (const int*)d_in[1];
    const int*   src         = (const int*)d_in[2];
    const int*   dst         = (const int*)d_in[3];
    const int*   t           = (const int*)d_in[4];
    const float* raw_msg     = (const float*)d_in[5];
    const float* time_w      = (const float*)d_in[6];
    const float* time_b      = (const float*)d_in[7];
    const float* w_ih        = (const float*)d_in[8];
    const float* w_hh        = (const float*)d_in[9];
    const float* b_ih        = (const float*)d_in[10];
    const float* b_hh        = (const float*)d_in[11];

    float* out = (float*)d_out;
    char* ws = (char*)d_ws;
    unsigned short* aggr  = (unsigned short*)(ws + OFF_AGGR);
    unsigned* cnt         = (unsigned*)(ws + OFF_CNT);
    int*      lastmax     = (int*)(ws + OFF_LAST);
    int*      offs        = (int*)(ws + OFF_OFFS);
    int*      cursor      = (int*)(ws + OFF_CUR);
    int4*     csr         = (int4*)(ws + OFF_CSR);
    short*    bpw         = (short*)(ws + OFF_BP);
    int*      partial     = (int*)(ws + OFF_PART);

    k_init<<<512, 256, 0, stream>>>(cnt, lastmax, w_ih, w_hh, bpw);
    k_count<<<(N_EVENTS + 255) / 256, 256, 0, stream>>>(src, dst, t, cnt, lastmax);
    k_scanA<<<SCAN_BLOCKS, 256, 0, stream>>>(cnt, partial);
    k_scanB<<<1, 128, 0, stream>>>(partial);
    k_scanC<<<SCAN_BLOCKS, 256, 0, stream>>>(cnt, partial, offs, cursor,
                                             lastmax, out + N_NODES * D);
    k_fill<<<(N_EVENTS + 255) / 256, 256, 0, stream>>>(src, dst, t, cursor, csr);
    k_aggr<<<N_NODES, 128, 0, stream>>>(memory, raw_msg, last_update, time_w, time_b,
                                        offs, cnt, csr, aggr);
    k_gemm_gru<<<(N_NODES + BM - 1) / BM, 512, 0, stream>>>(memory, aggr, cnt, bpw,
                                                            b_ih, b_hh, out);
}

// Round 10
// 265.137 us; speedup vs baseline: 1.0917x; 1.0917x over previous
//
#include <hip/hip_runtime.h>

#define N_NODES 100000
#define N_EVENTS 100000
#define D 128
#define KTOT 640
#define NP 512
#define BM 64

// ---- workspace layout (bytes) ----
#define OFF_AGGR 0                                 // bf16 [N][384] = 76,800,000
#define OFF_CNT  76800000
#define OFF_LAST (OFF_CNT  + N_NODES * 4)
#define OFF_OFFS (OFF_LAST + N_NODES * 4)
#define OFF_CUR  (OFF_OFFS + N_NODES * 4)
#define OFF_CSR  (OFF_CUR  + N_NODES * 4)          // int4 * 2E = 3,200,000
#define OFF_BP   (OFF_CSR  + 2 * N_EVENTS * 16)    // bf16 512*640 = 655,360
#define OFF_PART (OFF_BP   + NP * KTOT * 2)        // 98 ints

#define SCAN_BLOCKS 98   // ceil(100000 / 1024)

typedef __attribute__((ext_vector_type(8))) short bf16x8;
typedef __attribute__((ext_vector_type(4))) float f32x4;

__device__ __forceinline__ short f2bf(float x) {
    unsigned u = __float_as_uint(x);
    u = (u + 0x7FFFu + ((u >> 16) & 1u)) >> 16;
    return (short)u;
}

__device__ __forceinline__ bf16x8 cvt8(const float4& x0, const float4& x1) {
    bf16x8 h;
    h[0] = f2bf(x0.x); h[1] = f2bf(x0.y); h[2] = f2bf(x0.z); h[3] = f2bf(x0.w);
    h[4] = f2bf(x1.x); h[5] = f2bf(x1.y); h[6] = f2bf(x1.z); h[7] = f2bf(x1.w);
    return h;
}

#define MFMA(a, b, c) __builtin_amdgcn_mfma_f32_16x16x32_bf16(a, b, c, 0, 0, 0)

// ---- kernel 1: zero counters, build packed weight matrix Bp[512][640] bf16 ----
// Bp rows (n): 0-127 -> r (wih | whh), 128-255 -> z, 256-383 -> xn (k<512),
// 384-511 -> hn (k>=512 only)
__global__ __launch_bounds__(256) void k_init(unsigned* __restrict__ cnt,
                                              int* __restrict__ lastmax,
                                              const float* __restrict__ wih,
                                              const float* __restrict__ whh,
                                              short* __restrict__ bp) {
    int i = blockIdx.x * blockDim.x + threadIdx.x;
    int stride = gridDim.x * blockDim.x;
    for (int j = i; j < N_NODES; j += stride) { cnt[j] = 0u; lastmax[j] = 0; }
    for (int j = i; j < NP * KTOT; j += stride) {
        int n = j / KTOT, k = j - n * KTOT;
        float v = 0.f;
        if (n < 384) {
            if (k < 512) v = wih[n * 512 + k];
            else if (n < 256) v = whh[n * 128 + (k - 512)];
        } else if (k >= 512) {
            v = whh[(n - 128) * 128 + (k - 512)];
        }
        bp[j] = f2bf(v);
    }
}

// ---- kernel 2a: per-node degree count + last_update max ----
__global__ __launch_bounds__(256) void k_count(const int* __restrict__ src,
                                               const int* __restrict__ dst,
                                               const int* __restrict__ t,
                                               unsigned* __restrict__ cnt,
                                               int* __restrict__ lastmax) {
    int e = blockIdx.x * blockDim.x + threadIdx.x;
    if (e < N_EVENTS) {
        int s = src[e], d = dst[e], te = t[e];
        atomicAdd(&cnt[s], 1u);
        atomicAdd(&cnt[d], 1u);
        atomicMax(&lastmax[s], te);
        atomicMax(&lastmax[d], te);
    }
}

// ---- kernel 2b-1: per-block partial sums (1024 nodes/block) ----
__global__ __launch_bounds__(256) void k_scanA(const unsigned* __restrict__ cnt,
                                               int* __restrict__ partial) {
    const int b = blockIdx.x, tid = threadIdx.x;
    const int base = b * 1024 + tid * 4;
    int s = 0;
    if (base + 3 < N_NODES) {
        int4 c = *(const int4*)((const int*)cnt + base);
        s = c.x + c.y + c.z + c.w;
    } else {
        for (int k = 0; k < 4; ++k)
            if (base + k < N_NODES) s += (int)cnt[base + k];
    }
#pragma unroll
    for (int off = 32; off; off >>= 1) s += __shfl_down(s, off, 64);
    __shared__ int ws[4];
    if ((tid & 63) == 0) ws[tid >> 6] = s;
    __syncthreads();
    if (tid == 0) partial[b] = ws[0] + ws[1] + ws[2] + ws[3];
}

// ---- kernel 2b-2: exclusive scan of the 98 partials (tiny) ----
__global__ __launch_bounds__(128) void k_scanB(int* __restrict__ partial) {
    __shared__ int p[128];
    const int tid = threadIdx.x;
    p[tid] = (tid < SCAN_BLOCKS) ? partial[tid] : 0;
    __syncthreads();
    if (tid == 0) {
        int run = 0;
        for (int i = 0; i < SCAN_BLOCKS; ++i) { int v = p[i]; p[i] = run; run += v; }
    }
    __syncthreads();
    if (tid < SCAN_BLOCKS) partial[tid] = p[tid];
}

// ---- kernel 2b-3: block-local scan + offset -> offs, cursor; also emits
//      last_update output ----
__global__ __launch_bounds__(256) void k_scanC(const unsigned* __restrict__ cnt,
                                               const int* __restrict__ partial,
                                               int* __restrict__ offs,
                                               int* __restrict__ cursor,
                                               const int* __restrict__ lastmax,
                                               float* __restrict__ outLast) {
    __shared__ int sums[256];
    const int b = blockIdx.x, tid = threadIdx.x;
    const int base = b * 1024 + tid * 4;
    int c0 = 0, c1 = 0, c2 = 0, c3 = 0;
    if (base + 3 < N_NODES) {
        int4 c = *(const int4*)((const int*)cnt + base);
        c0 = c.x; c1 = c.y; c2 = c.z; c3 = c.w;
    } else {
        if (base     < N_NODES) c0 = (int)cnt[base];
        if (base + 1 < N_NODES) c1 = (int)cnt[base + 1];
        if (base + 2 < N_NODES) c2 = (int)cnt[base + 2];
        if (base + 3 < N_NODES) c3 = (int)cnt[base + 3];
    }
    sums[tid] = c0 + c1 + c2 + c3;
    __syncthreads();
    for (int off = 1; off < 256; off <<= 1) {
        int v = (tid >= off) ? sums[tid - off] : 0;
        __syncthreads();
        sums[tid] += v;
        __syncthreads();
    }
    int run = partial[b] + (tid > 0 ? sums[tid - 1] : 0);
    const int o0 = run, o1 = o0 + c0, o2 = o1 + c1, o3 = o2 + c2;
    if (base + 3 < N_NODES) {
        *(int4*)(offs + base)   = make_int4(o0, o1, o2, o3);
        *(int4*)(cursor + base) = make_int4(o0, o1, o2, o3);
        int4 lm = *(const int4*)(lastmax + base);
        float4 lo = make_float4((float)lm.x, (float)lm.y, (float)lm.z, (float)lm.w);
        *(float4*)(outLast + base) = lo;
    } else {
        if (base     < N_NODES) { offs[base]     = o0; cursor[base]     = o0; outLast[base]     = (float)lastmax[base]; }
        if (base + 1 < N_NODES) { offs[base + 1] = o1; cursor[base + 1] = o1; outLast[base + 1] = (float)lastmax[base + 1]; }
        if (base + 2 < N_NODES) { offs[base + 2] = o2; cursor[base + 2] = o2; outLast[base + 2] = (float)lastmax[base + 2]; }
        if (base + 3 < N_NODES) { offs[base + 3] = o3; cursor[base + 3] = o3; outLast[base + 3] = (float)lastmax[base + 3]; }
    }
}

// ---- kernel 2c: fill CSR records {other, t, e} ----
__global__ __launch_bounds__(256) void k_fill(const int* __restrict__ src,
                                              const int* __restrict__ dst,
                                              const int* __restrict__ t,
                                              int* __restrict__ cursor,
                                              int4* __restrict__ csr) {
    int e = blockIdx.x * blockDim.x + threadIdx.x;
    if (e < N_EVENTS) {
        int s = src[e], d = dst[e], te = t[e];
        int ps = atomicAdd(&cursor[s], 1);
        csr[ps] = make_int4(d, te, e, 0);
        int pd = atomicAdd(&cursor[d], 1);
        csr[pd] = make_int4(s, te, e, 0);
    }
}

// ---- kernel 3: gather-aggregate per node, write aggr bf16 [N][384] pre-divided ----
__global__ __launch_bounds__(128) void k_aggr(const float* __restrict__ mem,
                                              const float* __restrict__ raw,
                                              const int* __restrict__ lu,
                                              const float* __restrict__ tw,
                                              const float* __restrict__ tb,
                                              const int* __restrict__ offs,
                                              const unsigned* __restrict__ cnt,
                                              const int4* __restrict__ csr,
                                              unsigned short* __restrict__ aggr) {
    const int node = blockIdx.x;
    const int i = threadIdx.x;
    const unsigned deg = cnt[node];
    float a0 = 0.f, a1 = 0.f, a2 = 0.f;
    if (deg) {
        const int start = offs[node];
        const int lun = lu[node];
        const float wi = tw[i], bi = tb[i];
        for (unsigned j = 0; j < deg; ++j) {
            int4 rec = csr[start + j];
            const int other = rec.x, te = rec.y, e = rec.z;
            a0 += mem[other * D + i];
            a1 += raw[e * D + i];
            // match numpy: separate mul + add rounding (NO fma) before cos
            const float tr = (float)(te - lun);
            a2 += cosf(__fadd_rn(__fmul_rn(tr, wi), bi));
        }
        const float inv = 1.f / (float)deg;
        a0 *= inv; a1 *= inv; a2 *= inv;
    }
    aggr[node * 384 + i]       = (unsigned short)f2bf(a0);
    aggr[node * 384 + 128 + i] = (unsigned short)f2bf(a1);
    aggr[node * 384 + 256 + i] = (unsigned short)f2bf(a2);
}

// ---- kernel 4: fused concat-GEMM + GRU, single-barrier, free-running ----
// LDS chunk-major: sA[8 chunks][64 rows][64 elem bf16] (8 KB/chunk, 64 KB).
// Chunks 0-1 = mem raw (elems 0-63, 64-127); chunks 2-7 = aggr (pre-divided).
// Within a chunk, row r's 8 16B-slots are XOR-permuted: virtual slot v lives
// at byte ((v*16) ^ ((r&7)<<4)) — EXACT round-5/7 layout (measured 0 bank
// conflicts on both the staging write and the fragment read).
// K-schedule (20 steps, no barriers after the single staging barrier):
//   S 0-3:  chunks 0-1 (cnt>0-masked via cndmask) x B k 0-127   (wih; r,z,xn)
//   S 4-15: chunks 2-7                            x B k 128-511 (wih; r,z,xn)
//   S16-19: chunks 0-1 (raw)                      x B k 512-639 (whh; r,z,hn)

template<int S>
__device__ __forceinline__ void kstep(const short* __restrict__ sA,
                                      int lr, int lk, int swz,
                                      const short* __restrict__ bR,
                                      const short* __restrict__ bZ,
                                      const short* __restrict__ bN,
                                      const bool* mv,
                                      f32x4* accR, f32x4* accZ, f32x4* accN) {
    constexpr int chunk = (S < 4) ? (S >> 1) : (S < 16 ? 2 + ((S - 4) >> 1) : ((S - 16) >> 1));
    constexpr int k2 = S & 1;
    constexpr int kOff = (S < 16) ? S * 32 : 512 + (S - 16) * 32;
    bf16x8 fR = *(const bf16x8*)(bR + kOff);
    bf16x8 fZ = *(const bf16x8*)(bZ + kOff);
    bf16x8 fN = *(const bf16x8*)(bN + kOff);
    const int aoff = chunk * 8192 + lr * 128 + ((k2 * 64 + lk * 16) ^ swz);
#pragma unroll
    for (int mt = 0; mt < 4; ++mt) {
        bf16x8 a = *(const bf16x8*)((const char*)sA + mt * 2048 + aoff);
        if constexpr (S < 4) { const bf16x8 z = {}; a = mv[mt] ? a : z; }
        accR[mt] = MFMA(a, fR, accR[mt]);
        accZ[mt] = MFMA(a, fZ, accZ[mt]);
        accN[mt] = MFMA(a, fN, accN[mt]);
    }
}

__global__ __launch_bounds__(512, 4) void k_gemm_gru(const float* __restrict__ mem,
                                                     const unsigned short* __restrict__ aggr,
                                                     const unsigned* __restrict__ cnt,
                                                     const short* __restrict__ bp,
                                                     const float* __restrict__ bih,
                                                     const float* __restrict__ bhh,
                                                     float* __restrict__ out) {
    __shared__ short sA[8 * 64 * 64];   // 64 KB, chunk-major
    const int tid = threadIdx.x;
    const int node0 = blockIdx.x * BM;

    const int l = tid & 63, w = tid >> 6;
    const int lr = l & 15, lk = l >> 4;
    const int swz = (lr & 7) << 4;

    // ---- staging: thread (row_, cg) writes virtual slot cg of its row in
    // each of the 8 chunks (per-wave: 8 rows x 8 slots = contiguous 1 KB,
    // XOR-bijective per row -> conflict-free) ----
    const int row_ = tid >> 3;          // 0..63
    const int cg = tid & 7;
    const int nodeS = node0 + row_;
    const int ncS = nodeS < N_NODES ? nodeS : N_NODES - 1;
    const int wb = row_ * 128 + ((cg * 16) ^ ((row_ & 7) << 4));

    {
        const float4* memv = (const float4*)(mem + ncS * D);
        *(bf16x8*)((char*)sA + wb)        = cvt8(memv[cg * 2], memv[cg * 2 + 1]);
        *(bf16x8*)((char*)sA + 8192 + wb) = cvt8(memv[16 + cg * 2], memv[16 + cg * 2 + 1]);
#pragma unroll
        for (int j = 0; j < 6; ++j) {
            bf16x8 h = *(const bf16x8*)(aggr + ncS * 384 + (cg + 8 * j) * 8);
            *(bf16x8*)((char*)sA + (2 + j) * 8192 + wb) = h;
        }
    }

    // per-mt row validity mask (cnt>0) for the x-part
    bool mv[4];
#pragma unroll
    for (int mt = 0; mt < 4; ++mt) {
        const int node = node0 + mt * 16 + lr;
        mv[mt] = cnt[node < N_NODES ? node : N_NODES - 1] != 0u;
    }

    f32x4 accR[4], accZ[4], accNx[4], accNh[4];
#pragma unroll
    for (int mt = 0; mt < 4; ++mt) {
        accR[mt]  = (f32x4){0.f, 0.f, 0.f, 0.f};
        accZ[mt]  = (f32x4){0.f, 0.f, 0.f, 0.f};
        accNx[mt] = (f32x4){0.f, 0.f, 0.f, 0.f};
        accNh[mt] = (f32x4){0.f, 0.f, 0.f, 0.f};
    }

    const short* bR = bp + (w * 16 + lr) * KTOT + lk * 8;
    const short* bZ = bp + ((8 + w) * 16 + lr) * KTOT + lk * 8;
    const short* bX = bp + ((16 + w) * 16 + lr) * KTOT + lk * 8;
    const short* bH = bp + ((24 + w) * 16 + lr) * KTOT + lk * 8;

    __syncthreads();

    // ---- 20 unrolled K-steps, no barriers ----
    kstep< 0>(sA, lr, lk, swz, bR, bZ, bX, mv, accR, accZ, accNx);
    kstep< 1>(sA, lr, lk, swz, bR, bZ, bX, mv, accR, accZ, accNx);
    kstep< 2>(sA, lr, lk, swz, bR, bZ, bX, mv, accR, accZ, accNx);
    kstep< 3>(sA, lr, lk, swz, bR, bZ, bX, mv, accR, accZ, accNx);
    kstep< 4>(sA, lr, lk, swz, bR, bZ, bX, mv, accR, accZ, accNx);
    kstep< 5>(sA, lr, lk, swz, bR, bZ, bX, mv, accR, accZ, accNx);
    kstep< 6>(sA, lr, lk, swz, bR, bZ, bX, mv, accR, accZ, accNx);
    kstep< 7>(sA, lr, lk, swz, bR, bZ, bX, mv, accR, accZ, accNx);
    kstep< 8>(sA, lr, lk, swz, bR, bZ, bX, mv, accR, accZ, accNx);
    kstep< 9>(sA, lr, lk, swz, bR, bZ, bX, mv, accR, accZ, accNx);
    kstep<10>(sA, lr, lk, swz, bR, bZ, bX, mv, accR, accZ, accNx);
    kstep<11>(sA, lr, lk, swz, bR, bZ, bX, mv, accR, accZ, accNx);
    kstep<12>(sA, lr, lk, swz, bR, bZ, bX, mv, accR, accZ, accNx);
    kstep<13>(sA, lr, lk, swz, bR, bZ, bX, mv, accR, accZ, accNx);
    kstep<14>(sA, lr, lk, swz, bR, bZ, bX, mv, accR, accZ, accNx);
    kstep<15>(sA, lr, lk, swz, bR, bZ, bX, mv, accR, accZ, accNx);
    kstep<16>(sA, lr, lk, swz, bR, bZ, bH, mv, accR, accZ, accNh);
    kstep<17>(sA, lr, lk, swz, bR, bZ, bH, mv, accR, accZ, accNh);
    kstep<18>(sA, lr, lk, swz, bR, bZ, bH, mv, accR, accZ, accNh);
    kstep<19>(sA, lr, lk, swz, bR, bZ, bH, mv, accR, accZ, accNh);

    // epilogue: GRU gates. C layout: col = l&15 (-> jcol), row = (l>>4)*4 + i.
    const int jcol = w * 16 + lr;
    const float br  = bih[jcol]       + bhh[jcol];
    const float bz  = bih[128 + jcol] + bhh[128 + jcol];
    const float bxn = bih[256 + jcol];
    const float bhn = bhh[256 + jcol];
#pragma unroll
    for (int mt = 0; mt < 4; ++mt) {
#pragma unroll
        for (int i = 0; i < 4; ++i) {
            const int node = node0 + mt * 16 + lk * 4 + i;
            if (node < N_NODES) {
                const float rp = accR[mt][i] + br;
                const float zp = accZ[mt][i] + bz;
                const float xn = accNx[mt][i] + bxn;
                const float hn = accNh[mt][i] + bhn;
                const float rg = 1.f / (1.f + expf(-rp));
                const float zg = 1.f / (1.f + expf(-zp));
                const float ng = tanhf(xn + rg * hn);
                const float mo = mem[node * D + jcol];
                out[node * D + jcol] = (1.f - zg) * ng + zg * mo;
            }
        }
    }
}

extern "C" void kernel_launch(void* const* d_in, const int* in_sizes, int n_in,
                              void* d_out, int out_size, void* d_ws, size_t ws_size,
                              hipStream_t stream) {
    const float* memory      = (const float*)d_in[0];
    const int*   last_update = (const int*)d_in[1];
    const int*   src         = (const int*)d_in[2];
    const int*   dst         = (const int*)d_in[3];
    const int*   t           = (const int*)d_in[4];
    const float* raw_msg     = (const float*)d_in[5];
    const float* time_w      = (const float*)d_in[6];
    const float* time_b      = (const float*)d_in[7];
    const float* w_ih        = (const float*)d_in[8];
    const float* w_hh        = (const float*)d_in[9];
    const float* b_ih        = (const float*)d_in[10];
    const float* b_hh        = (const float*)d_in[11];

    float* out = (float*)d_out;
    char* ws = (char*)d_ws;
    unsigned short* aggr  = (unsigned short*)(ws + OFF_AGGR);
    unsigned* cnt         = (unsigned*)(ws + OFF_CNT);
    int*      lastmax     = (int*)(ws + OFF_LAST);
    int*      offs        = (int*)(ws + OFF_OFFS);
    int*      cursor      = (int*)(ws + OFF_CUR);
    int4*     csr         = (int4*)(ws + OFF_CSR);
    short*    bpw         = (short*)(ws + OFF_BP);
    int*      partial     = (int*)(ws + OFF_PART);

    k_init<<<512, 256, 0, stream>>>(cnt, lastmax, w_ih, w_hh, bpw);
    k_count<<<(N_EVENTS + 255) / 256, 256, 0, stream>>>(src, dst, t, cnt, lastmax);
    k_scanA<<<SCAN_BLOCKS, 256, 0, stream>>>(cnt, partial);
    k_scanB<<<1, 128, 0, stream>>>(partial);
    k_scanC<<<SCAN_BLOCKS, 256, 0, stream>>>(cnt, partial, offs, cursor,
                                             lastmax, out + N_NODES * D);
    k_fill<<<(N_EVENTS + 255) / 256, 256, 0, stream>>>(src, dst, t, cursor, csr);
    k_aggr<<<N_NODES, 128, 0, stream>>>(memory, raw_msg, last_update, time_w, time_b,
                                        offs, cnt, csr, aggr);
    k_gemm_gru<<<(N_NODES + BM - 1) / BM, 512, 0, stream>>>(memory, aggr, cnt, bpw,
                                                            b_ih, b_hh, out);
}